// Round 13
// baseline (120.195 us; speedup 1.0000x reference)
//
#include <hip/hip_runtime.h>
#include <hip/hip_bf16.h>

#define C 128
#define HW 4096
#define NPOS 65536
#define K 1024
#define MB 256           // positions per block
#define NBLK (NPOS/MB)   // 256 -> 1 block/CU
#define RS 136           // padded row stride in bf16 elems (272 B)
#define RSB 272          // row stride bytes

#define ZQ_OFF 0
#define LOSS_OFF 8388608
#define IDX_OFF 8388609
#define COMMIT_OFF 8454145
#define CODE_OFF 8454146

#define WS_IMG_OFF 8192  // bf16 codebook image at d_ws + 8192, 1024*272 B

// LDS must exceed 80 KB so only 1 block/CU fits -> 8 waves/CU -> 2 waves/EU
// -> VGPR budget 256 (r8/r9-verified rule). Pad inside the USED zt array
// (separate pad arrays get DCE'd, r8).
#define ZT_PAD 2048      // u16 elems = 4096 B

typedef __bf16 bf16x8 __attribute__((ext_vector_type(8)));
typedef float f32x4 __attribute__((ext_vector_type(4)));
typedef unsigned short u16x8 __attribute__((ext_vector_type(8)));

// Padded bf16 codebook image: row k = 128 bf16 (272B stride),
// fp32 (||e_k||^2 + 1.0) at row byte offset 256. Block 0 zeroes the loss
// accumulator S[0] and the completion ticket S[1].
__global__ void vq_prep(const float* __restrict__ emb, unsigned char* __restrict__ img,
                        float* __restrict__ S) {
    int k = blockIdx.x;
    int l = threadIdx.x;            // 64 threads
    if (k == 0 && l == 0) { S[0] = 0.0f; ((unsigned int*)S)[1] = 0u; }
    float v0 = emb[k * C + l];
    float v1 = emb[k * C + 64 + l];
    __hip_bfloat16 h0 = __float2bfloat16(v0);
    __hip_bfloat16 h1 = __float2bfloat16(v1);
    unsigned short* row = (unsigned short*)(img + (size_t)k * RSB);
    row[l] = *(unsigned short*)&h0;
    row[64 + l] = *(unsigned short*)&h1;
    float s = v0 * v0 + v1 * v1;
    #pragma unroll
    for (int off = 32; off; off >>= 1) s += __shfl_down(s, off);
    if (l == 0) *(float*)(img + (size_t)k * RSB + 256) = s + 1.0f;
}

// CODEBOOK-IN-REGISTERS structure (r12): each of the 8 waves pins its 128
// codes as MFMA B-fragments (32 x bf16x8 = 128 VGPRs + 8 norm f32), loaded
// ONCE from the L2-resident image, overlapped with the z stage. The main
// loop then streams 16 position-tiles from zt: per tile 4 ds_read_b128 ->
// 32 MFMA -> packed argmin. No bbuf, no barriers, no per-chunk B traffic --
// the per-chunk LDS/wait serialization that r0-r11 all shared is gone.
__global__ __launch_bounds__(512)
void vq_main(const float* __restrict__ z, const float* __restrict__ emb,
             const unsigned char* __restrict__ img,
             float* __restrict__ out, float* __restrict__ S) {
    __shared__ __align__(16) unsigned short zt[MB * RS + ZT_PAD];  // 73728 B
    __shared__ unsigned int wbest[8][MB];                          // 8192 B
    __shared__ unsigned short idxs[MB];                            // 512 B
    __shared__ float lred[8];
    // total 82464 B > 80 KB -> exactly 1 block/CU -> VGPR budget 256

    const int t = threadIdx.x;
    const int w = t >> 6;
    const int lane = t & 63;
    const int nn = lane & 15;      // MFMA: A row m / B col n / C col
    const int q = lane >> 4;       // quad
    const int wbase = w * 128;     // this wave's 128 codes: wbase..wbase+127

    const int blk = blockIdx.x;
    const int n0g = blk * MB;
    const int b = n0g >> 12;
    const int hw0 = n0g & (HW - 1);
    const float* zg = z + (size_t)b * C * HW + hw0;

    // ---- issue z loads FIRST (oldest in vmcnt queue: transpose waits on
    // these without draining the newer B loads) ----
    const int pos4 = (t & 63) * 4;
    const int c0 = (t >> 6) * 16;
    float4 fv[16];
    #pragma unroll
    for (int i = 0; i < 16; ++i)
        fv[i] = *(const float4*)&zg[(size_t)(c0 + i) * HW + pos4];

    // ---- issue B-fragment + norm loads (this wave's 128 codes, 8 n-tiles;
    // lane (nn,q) holds quarter-row q of code nt*16+nn) ----
    bf16x8 bp[8][4];
    float en[8];
    #pragma unroll
    for (int nt = 0; nt < 8; ++nt) {
        const unsigned char* rowp = img + (size_t)(wbase + nt * 16 + nn) * RSB;
        #pragma unroll
        for (int ks = 0; ks < 4; ++ks)
            bp[nt][ks] = *(const bf16x8*)(rowp + ks * 64 + q * 16);
        en[nt] = *(const float*)(rowp + 256);
    }
    // pin B fragments + norms resident for the whole loop (opaque to remat);
    // placed BEFORE the transpose so the loads can't be sunk below it
    #pragma unroll
    for (int nt = 0; nt < 8; ++nt) {
        #pragma unroll
        for (int ks = 0; ks < 4; ++ks)
            asm volatile("" : "+v"(*(f32x4*)&bp[nt][ks]));
        asm volatile("" : "+v"(en[nt]));
    }

    // ---- transpose z -> LDS bf16 [pos][c] (row stride 272B) ----
    #pragma unroll
    for (int j = 0; j < 4; ++j) {
        u16x8 p0, p1;
        #pragma unroll
        for (int i = 0; i < 8; ++i) {
            float f0 = (j == 0) ? fv[i].x : (j == 1) ? fv[i].y
                     : (j == 2) ? fv[i].z : fv[i].w;
            float f1 = (j == 0) ? fv[8 + i].x : (j == 1) ? fv[8 + i].y
                     : (j == 2) ? fv[8 + i].z : fv[8 + i].w;
            __hip_bfloat16 h0 = __float2bfloat16(f0);
            __hip_bfloat16 h1 = __float2bfloat16(f1);
            p0[i] = *(unsigned short*)&h0;
            p1[i] = *(unsigned short*)&h1;
        }
        *(u16x8*)&zt[(pos4 + j) * RS + c0] = p0;
        *(u16x8*)&zt[(pos4 + j) * RS + c0 + 8] = p1;
    }
    __syncthreads();   // zt ready; the ONLY barrier before the reduction

    // ---- main loop: 16 position-tiles, zero barriers, no global traffic.
    // Per tile: 4 ds_read_b128 (A) -> 32 MFMA -> packed argmin -> wbest.
    // Waves staggered by tile to spread LDS pressure. ----
    const int mt0 = (w * 2) & 15;
    for (int i = 0; i < 16; ++i) {
        const int mt = (mt0 + i) & 15;
        bf16x8 zf[4];
        #pragma unroll
        for (int ks = 0; ks < 4; ++ks)
            zf[ks] = *(bf16x8*)&zt[(mt * 16 + nn) * RS + ks * 32 + q * 8];

        f32x4 acc[8];
        #pragma unroll
        for (int nt = 0; nt < 8; ++nt) acc[nt] = (f32x4){0.f, 0.f, 0.f, 0.f};
        #pragma unroll
        for (int ks = 0; ks < 4; ++ks)
            #pragma unroll
            for (int nt = 0; nt < 8; ++nt)
                acc[nt] = __builtin_amdgcn_mfma_f32_16x16x32_bf16(zf[ks], bp[nt][ks], acc[nt], 0, 0, 0);

        // packed argmin: score' = (enorm+1) - 2*dot (always ~1.0 > 0),
        // clear low 10 mantissa bits, OR in code; u32 min == float min + tie-low.
        unsigned int best4[4] = {0xFFFFFFFFu, 0xFFFFFFFFu, 0xFFFFFFFFu, 0xFFFFFFFFu};
        #pragma unroll
        for (int nt = 0; nt < 8; ++nt) {
            const unsigned int codent = (unsigned int)(wbase + nt * 16 + nn);
            #pragma unroll
            for (int r = 0; r < 4; ++r) {
                float s = fmaf(acc[nt][r], -2.0f, en[nt]);
                unsigned int u = (__float_as_uint(s) & ~1023u) | codent;
                best4[r] = min(best4[r], u);
            }
        }
        // reduce over the 16 code-columns (xor lanes 1,2,4,8 stay in quad)
        #pragma unroll
        for (int r = 0; r < 4; ++r) {
            unsigned int v = best4[r];
            v = min(v, (unsigned int)__shfl_xor((int)v, 1));
            v = min(v, (unsigned int)__shfl_xor((int)v, 2));
            v = min(v, (unsigned int)__shfl_xor((int)v, 4));
            v = min(v, (unsigned int)__shfl_xor((int)v, 8));
            if (nn == 0) wbest[w][mt * 16 + q * 4 + r] = v;   // per-wave best
        }
    }
    __syncthreads();

    if (t < MB) {
        unsigned int v = wbest[0][t];
        #pragma unroll
        for (int i = 1; i < 8; ++i) v = min(v, wbest[i][t]);
        unsigned int code = v & 1023u;
        idxs[t] = (unsigned short)code;
        out[IDX_OFF + n0g + t] = (float)code;
    }
    __syncthreads();

    // epilogue: per-position emb gather, register transpose, float4 z_q
    // stores along pos, exact fp32 loss vs the bf16 zt values
    {
        float* og = out + ZQ_OFF + (size_t)b * C * HW + hw0;
        float ev[4][16];
        float ls = 0.f;
        #pragma unroll
        for (int j = 0; j < 4; ++j) {
            const int pos = pos4 + j;
            const float* erow = emb + (size_t)idxs[pos] * C;
            #pragma unroll
            for (int g = 0; g < 4; ++g) {
                float4 e = *(const float4*)&erow[c0 + g * 4];
                ev[j][g * 4 + 0] = e.x; ev[j][g * 4 + 1] = e.y;
                ev[j][g * 4 + 2] = e.z; ev[j][g * 4 + 3] = e.w;
            }
            u16x8 z0 = *(u16x8*)&zt[pos * RS + c0];
            u16x8 z1 = *(u16x8*)&zt[pos * RS + c0 + 8];
            #pragma unroll
            for (int i = 0; i < 8; ++i) {
                float zf0 = __uint_as_float((unsigned int)z0[i] << 16);
                float zf1 = __uint_as_float((unsigned int)z1[i] << 16);
                float d0 = zf0 - ev[j][i];
                float d1 = zf1 - ev[j][8 + i];
                ls += d0 * d0 + d1 * d1;
            }
        }
        #pragma unroll
        for (int i = 0; i < 16; ++i) {
            float4 v = { ev[0][i], ev[1][i], ev[2][i], ev[3][i] };
            *(float4*)&og[(size_t)(c0 + i) * HW + pos4] = v;
        }
        #pragma unroll
        for (int off = 32; off; off >>= 1) ls += __shfl_down(ls, off);
        if (lane == 0) lred[w] = ls;
    }
    __syncthreads();

    // fused finalization, NO fences (r2 regression was 512 device fences):
    // asm consumes the S-add's return (forces its completion) and "memory"
    // keeps the ticket add after it; winner reads the total via volatile load.
    if (t == 0) {
        float bs = 0.f;
        #pragma unroll
        for (int i = 0; i < 8; ++i) bs += lred[i];
        float prev = atomicAdd(S, bs);
        asm volatile("" :: "v"(prev) : "memory");
        unsigned int old = atomicAdd((unsigned int*)S + 1, 1u);
        if (old == NBLK - 1) {
            float s = atomicAdd(S, 0.0f);   // coherent RMW read of the total
            out[LOSS_OFF] = 1.25f * s;
            out[COMMIT_OFF] = 0.25f * s;
            out[CODE_OFF] = s;
        }
    }
}

extern "C" void kernel_launch(void* const* d_in, const int* in_sizes, int n_in,
                              void* d_out, int out_size, void* d_ws, size_t ws_size,
                              hipStream_t stream) {
    const float* z = (const float*)d_in[0];
    const float* emb = (const float*)d_in[1];
    float* out = (float*)d_out;
    float* S = (float*)d_ws;
    unsigned char* img = (unsigned char*)d_ws + WS_IMG_OFF;   // needs ~287 KB of ws

    vq_prep<<<K, 64, 0, stream>>>(emb, img, S);
    vq_main<<<NBLK, 512, 0, stream>>>(z, emb, img, out, S);
}